// Round 7
// baseline (543.481 us; speedup 1.0000x reference)
//
#include <hip/hip_runtime.h>

// LSTMModel: 4-layer LSTM (H=50, IN=7, B=1024, T=512) + FC(50->25 relu ->1).
// R15: windowed wave-per-layer recurrence (R11's dataflow, both killers fixed).
//
// Model (fits R8-R14): MfmaUtil x tick = ~810-880cy invariant across all
// partitions = 182 MFMAs x 4.85cy/MFMA per-CU matrix-pipe service time. The
// per-tick barrier locksteps every wave through [read->MFMA->trans->store],
// so the tick is the serial chain (~2100cy), not any pipe floor. Fix: barrier
// per WINDOW of W=4 ticks (135 barriers, not 515). ONE wave owns a layer's
// recurrence; within a window it runs 4 serial ticks with intra-wave LDS
// RAW only (in-order DS + lgkmcnt). A second wave per layer computes the
// input-half pre(t)=Wih*h_below+b one window ahead into f32 LDS.
// R11's spill: launch_bounds(512,2) capped VGPR at 128 (observed) -> use
// (512,1): 8-wave block forces <=256/wave, demand ~215. R12's LDS flood:
// pre traffic cut 13+13 -> 4+4 LDS instrs/lane-tick: rec reads ONLY its 4
// owned units' float4 (gate-major rows: unit u's 4 gates = contiguous
// float4) and adds after extraction (not C-init); input writes via
// tsel-distributed cndmask-select (4 b128 stores, all lanes active).
//
// Schedule: window w (barrier at end): input-l computes pre for tick-block
// (w-2l) -> preb[l][(w+1)&1]; rec-l processes block (w-2l-1) reading
// preb[l][w&1] + own hring (slots t&7; blocks alternate 4-slot halves so
// same-window cross-wave reads never touch this window's writes -- verified
// per pair). Budget/window/CU: MFMA 780x4.85=3783cy (floor), VALU ~2040/SIMD,
// LDS ~2600 -> MFMA-bound ~215us ideal. Rec waves run persistent setprio(1)
// (rec=critical chain, input=filler: true role asymmetry, T5's regime).
// exp2 constants folded into weights+bias (R10). pre f32 (exact numerics).

#define H 50
#define INSZ 7
#define TT 512
#define NL 4
#define FC1N 25
#define BPG 4
#define NBLK 256
#define NTHREADS 512
#define NCH 13        // M-chunks of 16 gate-rows (208 >= 200)
#define WT 4          // ticks per window
#define NWIN 135      // windows: rec-3 block 127 at w = 127+2*3+1 = 134
#define HRS 80        // hring row stride in halves
#define PRS 208       // pre row stride in floats (= 16*NCH)
#define XD 32         // x ring depth (ticks)
#define XW 32         // x ring row stride in halves (8..31 stay zero)

typedef _Float16 half_t;
typedef __attribute__((ext_vector_type(8))) _Float16 half8_t;
typedef __attribute__((ext_vector_type(4))) float float4_t;

struct Params {
  const float* x;
  const float* Wih[NL];
  const float* Whh[NL];
  const float* bih[NL];
  const float* bhh[NL];
  const float* W1;
  const float* b1;
  const float* W2;
  const float* b2;
  float* out;
};

#define MFMA16(A, B, C) __builtin_amdgcn_mfma_f32_16x16x32_f16((A), (B), (C), 0, 0, 0)
#define EXP2F(x) __builtin_amdgcn_exp2f(x)
#define RCPF(x) __builtin_amdgcn_rcpf(x)

// Gate update: g = pre-scaled (i,f,g,o) pre-acts; c = cell (in/out); h = out.
#define UPD(g, c, h)                                                     \
  const float di = 1.0f + EXP2F((g)[0]);                                 \
  const float df = 1.0f + EXP2F((g)[1]);                                 \
  const float dgg = 1.0f + EXP2F((g)[2]);                                \
  const float dq = 1.0f + EXP2F((g)[3]);                                 \
  const float r1 = RCPF(di * df);                                        \
  const float r2 = RCPF(dgg * dq);                                       \
  const float gi = r1 * df;                                              \
  const float gf = r1 * di;                                              \
  const float gg = 2.0f * (r2 * dq) - 1.0f;                              \
  const float go = r2 * dgg;                                             \
  (c) = gf * (c) + gi * gg;                                              \
  const float dc = 1.0f + EXP2F(-2.885390082f * (c));                    \
  const float h = go * (2.0f * RCPF(dc) - 1.0f);

__device__ __forceinline__ float4_t sel4(int t, float4_t a, float4_t b,
                                         float4_t c, float4_t d) {
  const float4_t ab = (t & 1) ? b : a;
  const float4_t cd = (t & 1) ? d : c;
  return (t & 2) ? cd : ab;
}

__global__ __launch_bounds__(NTHREADS, 1) void lstm_r15(Params p) {
  __shared__ __align__(16) half_t hring[NL][8][BPG][HRS];   // h ring; 1.0@50
  __shared__ __align__(16) half_t xring[XD][BPG][XW];       // x ring; 1.0@7
  __shared__ __align__(16) float preb[NL][2][WT][BPG][PRS]; // input-half, f32
  __shared__ float fc1_buf[BPG][FC1N];

  const int tid = threadIdx.x;
  const int b0 = blockIdx.x * BPG;
  const int lane = tid & 63;
  const int quad = lane >> 4;
  const int col = lane & 15;
  const int wid = tid >> 6;      // 0..7
  const bool isrec = (wid < 4);  // 0..3: recurrence; 4..7: input GEMM
  const int lay = wid & 3;
  const int bb = col & 3;
  const int tsel = col >> 2;

  // ---- A fragments af[cc][kg]: chunk cc covers gate-rows r = cc*16 + col;
  //      unit-major r=4u+q -> u = cc*4+tsel, q = col&3; k = kg*32+quad*8+j.
  //      rec: Whh (k<50).  input l==0: Wih0 k<7, bias k==7 (kg0 only used).
  //      input l>=1: Wih k<50, bias k==50. Pre-scaled by the gate's exp2
  //      constant (q==2 -> -2.885390082, else -1.442695041).
  half8_t af[NCH][2];
  {
    const int q = col & 3;
#pragma unroll
    for (int cc = 0; cc < NCH; ++cc) {
      const int u = cc * 4 + tsel;
#pragma unroll
      for (int kg = 0; kg < 2; ++kg) {
        half8_t v;
#pragma unroll
        for (int j = 0; j < 8; ++j) {
          const int k = kg * 32 + quad * 8 + j;
          float wv = 0.0f;
          if (u < H) {
            const int row = q * H + u;
            if (isrec) {
              if (k < H) wv = p.Whh[lay][row * H + k];
            } else if (lay == 0) {
              if (k < INSZ) wv = p.Wih[0][row * INSZ + k];
              else if (k == INSZ) wv = p.bih[0][row] + p.bhh[0][row];
            } else {
              if (k < H) wv = p.Wih[lay][row * H + k];
              else if (k == H) wv = p.bih[lay][row] + p.bhh[lay][row];
            }
            wv *= (q == 2) ? -2.885390082f : -1.442695041f;
          }
          v[j] = (half_t)wv;
        }
        af[cc][kg] = v;
      }
    }
  }

  // ---- init LDS ----
  {
    unsigned* hz = (unsigned*)hring;
    for (int i = tid; i < (int)(NL * 8 * BPG * HRS / 2); i += NTHREADS) hz[i] = 0u;
    unsigned* xz = (unsigned*)xring;
    for (int i = tid; i < (int)(XD * BPG * XW / 2); i += NTHREADS) xz[i] = 0u;
  }
  __syncthreads();
  if (tid < NL * 8 * BPG) {  // hring bias-1.0 at slot H (all ring slots)
    const int l = tid >> 5, sl = (tid >> 2) & 7, b = tid & 3;
    hring[l][sl][b][H] = (half_t)1.0f;
  } else if (tid < NL * 8 * BPG + XD * BPG) {  // xring bias-1.0 at slot 7
    const int i = tid - NL * 8 * BPG;
    xring[i >> 2][i & 3][INSZ] = (half_t)1.0f;
  }
  // x prefill t = 0..31
  for (int i = tid; i < XD * BPG * INSZ; i += NTHREADS) {
    const int t = i / (BPG * INSZ), rem = i % (BPG * INSZ);
    const int b = rem / INSZ, k = rem % INSZ;
    xring[t][b][k] = (half_t)p.x[((size_t)(b0 + b) * TT + t) * INSZ + k];
  }
  __syncthreads();

  // rec waves: persistent priority (critical chain); input waves are filler.
  if (isrec) __builtin_amdgcn_s_setprio(1);

  float cst0 = 0.0f, cst1 = 0.0f, cst2 = 0.0f, cst3 = 0.0f;
  const float4_t fz = {0.0f, 0.0f, 0.0f, 0.0f};
  const bool v3ok = (tsel == 0) && (quad < 2);     // j=3 valid (u=48,49)
  const int off3 = v3ok ? (192 + 4 * quad) : 0;    // clamped pre offset

  // Rec tick: 2-deep MFMA chains (own-half K=64) -> per-j extract (+pre) ->
  // UPD -> h store. lgkmcnt(0) at end orders the intra-window LDS RAW.
#define REC_TICK(T_, PRT_)                                                      \
  {                                                                             \
    const half_t* hb = &hring[lay][((T_) - 1) & 7][bb][quad * 8];               \
    const half8_t v0 = *(const half8_t*)(hb);                                   \
    const half8_t v1 = *(const half8_t*)(hb + 32);                              \
    const float* prr = (PRT_) + bb * PRS;                                       \
    const float4_t pj0 = *(const float4_t*)(prr + 16 * tsel + 4 * quad);        \
    const float4_t pj1 = *(const float4_t*)(prr + 64 + 16 * tsel + 4 * quad);   \
    const float4_t pj2 = *(const float4_t*)(prr + 128 + 16 * tsel + 4 * quad);  \
    const float4_t pj3 = *(const float4_t*)(prr + off3);                        \
    float4_t acc[NCH];                                                          \
    _Pragma("unroll") for (int cc = 0; cc < NCH; ++cc)                          \
        acc[cc] = MFMA16(af[cc][0], v0, fz);                                    \
    _Pragma("unroll") for (int cc = 0; cc < NCH; ++cc)                          \
        acc[cc] = MFMA16(af[cc][1], v1, acc[cc]);                               \
    half_t* hw = &hring[lay][(T_) & 7][bb][0];                                  \
    {                                                                           \
      const float4_t ga = sel4(tsel, acc[0], acc[1], acc[2], acc[3]) + pj0;     \
      UPD(ga, cst0, h0v)                                                        \
      hw[4 * tsel + quad] = (half_t)h0v;                                        \
    }                                                                           \
    {                                                                           \
      const float4_t ga = sel4(tsel, acc[4], acc[5], acc[6], acc[7]) + pj1;     \
      UPD(ga, cst1, h1v)                                                        \
      hw[16 + 4 * tsel + quad] = (half_t)h1v;                                   \
    }                                                                           \
    {                                                                           \
      const float4_t ga = sel4(tsel, acc[8], acc[9], acc[10], acc[11]) + pj2;   \
      UPD(ga, cst2, h2v)                                                        \
      hw[32 + 4 * tsel + quad] = (half_t)h2v;                                   \
    }                                                                           \
    {                                                                           \
      const float4_t ga = sel4(tsel, acc[12], acc[12], acc[12], acc[12]) + pj3; \
      UPD(ga, cst3, h3v)                                                        \
      if (v3ok) hw[48 + quad] = (half_t)h3v;                                    \
    }                                                                           \
    asm volatile("s_waitcnt lgkmcnt(0)" ::: "memory");                          \
  }

  // Input tick: pre(t) = Wih*h_below + bias (K=64; L0: K=32) -> 4 b128
  // stores, tsel-distributed (chunk cc = 4*tsel + i written by tsel group).
#define IN_TICK(T_, PWT_)                                                       \
  {                                                                             \
    const half_t* hb = (lay == 0) ? &xring[(T_) & 31][bb][quad * 8]             \
                                  : &hring[lay - 1][(T_) & 7][bb][quad * 8];    \
    const half8_t v0 = *(const half8_t*)(hb);                                   \
    float4_t acc[NCH];                                                          \
    if (lay == 0) {                                                             \
      _Pragma("unroll") for (int cc = 0; cc < NCH; ++cc)                        \
          acc[cc] = MFMA16(af[cc][0], v0, fz);                                  \
    } else {                                                                    \
      const half8_t v1 = *(const half8_t*)(hb + 32);                            \
      _Pragma("unroll") for (int cc = 0; cc < NCH; ++cc)                        \
          acc[cc] = MFMA16(af[cc][0], v0, fz);                                  \
      _Pragma("unroll") for (int cc = 0; cc < NCH; ++cc)                        \
          acc[cc] = MFMA16(af[cc][1], v1, acc[cc]);                             \
    }                                                                           \
    float* pw = (PWT_) + bb * PRS + 64 * tsel + 4 * quad;                       \
    *(float4_t*)(pw) = sel4(tsel, acc[0], acc[4], acc[8], acc[12]);             \
    if (tsel < 3) {                                                             \
      *(float4_t*)(pw + 16) = sel4(tsel, acc[1], acc[5], acc[9], acc[9]);       \
      *(float4_t*)(pw + 32) = sel4(tsel, acc[2], acc[6], acc[10], acc[10]);     \
      *(float4_t*)(pw + 48) = sel4(tsel, acc[3], acc[7], acc[11], acc[11]);     \
    }                                                                           \
  }

  // ---- window loop ----
  for (int w = 0; w < NWIN; ++w) {
    if (isrec) {
      const int blk = w - 2 * lay - 1;
      if ((unsigned)blk < 128u) {
        const float* prw = &preb[lay][w & 1][0][0][0];
#pragma unroll
        for (int tw = 0; tw < WT; ++tw) {
          const int t = 4 * blk + tw;
          REC_TICK(t, prw + tw * (BPG * PRS))
        }
      }
    } else {
      const int blk2 = w - 2 * lay;
      if ((unsigned)blk2 < 128u) {
        float* pww = &preb[lay][(w + 1) & 1][0][0][0];
#pragma unroll
        for (int tw = 0; tw < WT; ++tw) {
          const int t2 = 4 * blk2 + tw;
          IN_TICK(t2, pww + tw * (BPG * PRS))
        }
        // x ring refill (input-0): every 4th block, load 16 ticks ahead
        if (lay == 0 && blk2 > 0 && (blk2 & 3) == 0 && 4 * blk2 + 16 < TT) {
          const int toff = lane >> 2, xb = lane & 3;
          const int t0 = 4 * blk2 + 16 + toff;
          const float* src = &p.x[((size_t)(b0 + xb) * TT + t0) * INSZ];
          half_t* dst = &xring[t0 & 31][xb][0];
#pragma unroll
          for (int k = 0; k < INSZ; ++k) dst[k] = (half_t)src[k];
        }
      }
    }
    __syncthreads();
  }

  // ---- FC head (fp32); h_3(511) is in hring[3][511&7 = 7] ----
  if (tid < BPG * FC1N) {
    const int b = tid / FC1N, j = tid % FC1N;
    const float* wgt = p.W1 + j * H;
    float a = p.b1[j];
#pragma unroll
    for (int k = 0; k < H; ++k)
      a += (float)hring[3][7][b][k] * wgt[k];
    fc1_buf[b][j] = fmaxf(a, 0.0f);
  }
  __syncthreads();
  if (tid < BPG) {
    float a = p.b2[0];
#pragma unroll
    for (int j = 0; j < FC1N; ++j) a += fc1_buf[tid][j] * p.W2[j];
    p.out[b0 + tid] = a;
  }
}

extern "C" void kernel_launch(void* const* d_in, const int* in_sizes, int n_in,
                              void* d_out, int out_size, void* d_ws, size_t ws_size,
                              hipStream_t stream) {
  Params p;
  p.x = (const float*)d_in[0];
  for (int l = 0; l < NL; ++l) {
    p.Wih[l] = (const float*)d_in[1 + 4 * l];
    p.Whh[l] = (const float*)d_in[2 + 4 * l];
    p.bih[l] = (const float*)d_in[3 + 4 * l];
    p.bhh[l] = (const float*)d_in[4 + 4 * l];
  }
  p.W1 = (const float*)d_in[17];
  p.b1 = (const float*)d_in[18];
  p.W2 = (const float*)d_in[19];
  p.b2 = (const float*)d_in[20];
  p.out = (float*)d_out;

  hipLaunchKernelGGL(lstm_r15, dim3(NBLK), dim3(NTHREADS), 0, stream, p);
}